// Round 2
// baseline (246.843 us; speedup 1.0000x reference)
//
#include <hip/hip_runtime.h>
#include <math.h>

// ToneStack: 3 cascaded shelf biquads over x[64, 480000] fp32.
//
// R6: wave-coalesced LOADS via global_load_lds + per-wave independence.
//   R5 fixed the store side (wave-contiguous 1KB stores via LDS transpose,
//   137->92us). rocprof showed the load side still had the same pathology:
//   16 global_load_dwordx4 per thread at 256B inter-lane stride -> each
//   wave load touches 64 distinct 128B lines (8x L1/L2 request
//   amplification, L1 thrash at 8 waves x 16KB footprints).
//   Now each wave DMAs its 16KB tile into a private LDS buffer with 16
//   lane-contiguous 1KB global_load_lds transfers. Source addresses are
//   pre-swizzled (linear LDS dest + inverse-swizzled source + swizzled
//   ds_read: XOR (slot&7)<<4, an involution, conflict-free b128 reads).
//   Pass1/pass2 read x from LDS; pass2 writes y back in place; the same
//   buffer feeds the wave-contiguous store -> store path now per-wave
//   independent (0 barriers). A^64 moved from LDS (12 barriers) to
//   per-wave shuffle squarings with the identical fma sequence -> output
//   bitwise identical to R5 (absmax 0.03125). One __syncthreads remains
//   (d exchange for the cross-wave Horner).
//   LDS 71KB -> 2 blocks/CU -> grid becomes ~4 cohorts: each CU overlaps
//   one block's store burst with the next block's DMA loads.

constexpr int T_LEN  = 480000;
constexpr int B_ROWS = 64;
constexpr int CHUNK  = 64;
constexpr int LOG2C  = 6;                     // A^64 = 6 squarings
constexpr int KCH    = T_LEN / CHUNK;         // 7500 chunks per row
constexpr int NT     = 256;                   // threads per block
constexpr int HISTC  = 24;                    // history chunks (1536 samples)
constexpr int MTERM  = 24;                    // Horner terms (= horizon)
constexpr int OUTC   = NT - HISTC;            // 232 output chunks per block
constexpr int BLKROW = (KCH + OUTC - 1) / OUTC;  // 33 blocks per row
constexpr int NBLK   = B_ROWS * BLKROW;       // 2112 blocks
constexpr long long XBYTES = (long long)B_ROWS * T_LEN * 4;

struct Coeffs { float b0, b1, b2, a1, a2; };

typedef __attribute__((address_space(1))) const void GV;
typedef __attribute__((address_space(3))) void LV;

__device__ __forceinline__ void gload_lds16(const void* g, void* l) {
    __builtin_amdgcn_global_load_lds((GV*)g, (LV*)l, 16, 0, 0);
}

__device__ __forceinline__ float rfl(float v) {
    return __int_as_float(__builtin_amdgcn_readfirstlane(__float_as_int(v)));
}

__device__ __forceinline__ Coeffs shelf(float fc, float gdb, float Q) {
    float A  = powf(10.0f, gdb * (1.0f / 40.0f));
    float w0 = 2.0f * 3.14159265358979323846f * fc / 48000.0f;
    float sw = sinf(w0), cw = cosf(w0);
    float alpha = sw / (2.0f * Q);
    float sqA = sqrtf(A);
    float b0 = A * ((A + 1.0f) - (A - 1.0f) * cw + 2.0f * sqA * alpha);
    float b1 = 2.0f * A * ((A - 1.0f) - (A + 1.0f) * cw);
    float b2 = A * ((A + 1.0f) - (A - 1.0f) * cw - 2.0f * sqA * alpha);
    float a0 = (A + 1.0f) + (A - 1.0f) * cw + 2.0f * sqA * alpha;
    float a1 = -2.0f * ((A - 1.0f) + (A + 1.0f) * cw);
    float a2 = (A + 1.0f) + (A - 1.0f) * cw - 2.0f * sqA * alpha;
    float rr = 1.0f / a0;
    Coeffs c;
    c.b0 = rfl(b0 * rr); c.b1 = rfl(b1 * rr); c.b2 = rfl(b2 * rr);
    c.a1 = rfl(a1 * rr); c.a2 = rfl(a2 * rr);
    return c;
}

// DF2T biquad step, op-for-op as reference:
//   y = b0*x + z1; z1' = b1*x - a1*y + z2; z2' = b2*x - a2*y
__device__ __forceinline__ float bq(float xn, const Coeffs& c, float& z1, float& z2) {
    float y = fmaf(c.b0, xn, z1);
    z1 = fmaf(-c.a1, y, fmaf(c.b1, xn, z2));
    z2 = fmaf(c.b2, xn, -(c.a2 * y));
    return y;
}

__device__ __forceinline__ float step6(float s[6], float x,
                                       const Coeffs& c1, const Coeffs& c2, const Coeffs& c3) {
    float y1 = bq(x,  c1, s[0], s[1]);
    float y2 = bq(y1, c2, s[2], s[3]);
    float y3 = bq(y2, c3, s[4], s[5]);
    return y3;
}

__global__ __launch_bounds__(256, 2) void k_fused(
    const float* __restrict__ x,
    const float* __restrict__ p_lg, const float* __restrict__ p_mg,
    const float* __restrict__ p_mf, const float* __restrict__ p_mq,
    const float* __restrict__ p_hg,
    float* __restrict__ out)
{
    // [0 .. 16384): four per-wave 16KB x/y staging buffers (swizzled layout)
    // [16384 .. 18176): per-thread d store, stride 7 (bank-conflict-free)
    __shared__ __align__(16) float smem[16384 + NT * 7];

    const int t    = threadIdx.x;
    const int lane = t & 63;
    const int w    = t >> 6;
    const int r = blockIdx.x / BLKROW;
    const int b = blockIdx.x - r * BLKROW;
    const int c = b * OUTC + t - HISTC;          // this thread's chunk index
    const int cbase = b * OUTC - HISTC;          // chunk index of thread 0
    const bool active = (c >= 0) && (c < KCH);

    // Coeffs first: their (uniform) loads resolve before the DMA queue
    // fills, so no coeff-use waitcnt drains the tile loads.
    Coeffs c1 = shelf(120.0f,  *p_lg, 0.707f);
    Coeffs c2 = shelf(*p_mf,   *p_mg, *p_mq);
    Coeffs c3 = shelf(4000.0f, *p_hg, 0.707f);
    __builtin_amdgcn_sched_barrier(0);

    // ---- wave-coalesced DMA: this wave's 16KB tile -> LDS (swizzled) ----
    // LDS dest is linear (base + lane*16 per instr); the swizzle
    // byte' = byte ^ ((slot&7)<<4) is applied by inverse-permuting the
    // GLOBAL source address (involution: XOR bits 4..6 keyed on bits 8..10).
    float* svw = smem + w * 4096;
    {
        long long wbyte = ((long long)r * T_LEN + (long long)(cbase + w * 64) * CHUNK) * 4;
        #pragma unroll
        for (int k = 0; k < 16; ++k) {
            int d = k * 1024 + lane * 16;
            int srel = d ^ (((d >> 8) & 7) << 4);
            long long g = wbyte + srel;
            g = g < 0 ? 0 : (g > XBYTES - 16 ? XBYTES - 16 : g);  // clamp (masked lanes)
            gload_lds16((const char*)x + g, (char*)svw + k * 1024);
        }
    }

    // ---- A^64 per-wave via shuffles (identical fma sequence as the LDS
    //      version: acc=0; acc=fma(A[i][q],A[q][j],acc) per squaring) ----
    float a[36];
    {
        const int i = lane / 6;                  // row  (lanes >=36 garbage, unused)
        const int j = lane - 6 * i;              // col
        float e[6];
        #pragma unroll
        for (int jj = 0; jj < 6; ++jj) e[jj] = (j == jj) ? 1.0f : 0.0f;
        step6(e, 0.0f, c1, c2, c3);              // column j of A
        float aM = e[0];
        #pragma unroll
        for (int ii = 1; ii < 6; ++ii) aM = (i == ii) ? e[ii] : aM;
        const int i6 = i * 6;
        for (int it = 0; it < LOG2C; ++it) {
            float acc = 0.f;
            #pragma unroll
            for (int q = 0; q < 6; ++q) {
                int sA = i6 + q; if (sA > 63) sA = 63;   // lanes >=36 only
                float lhs = __shfl(aM, sA, 64);          // A[i][q]
                float rhs = __shfl(aM, q * 6 + j, 64);   // A[q][j]
                acc = fmaf(lhs, rhs, acc);
            }
            aM = acc;
        }
        #pragma unroll
        for (int k = 0; k < 36; ++k) a[k] = rfl(__shfl(aM, k, 64));
    }

    // ---- pass 1: zero-state response, reading x from LDS ----
    asm volatile("s_waitcnt vmcnt(0)" ::: "memory");
    __builtin_amdgcn_sched_barrier(0);
    const int sb = lane * 16;                    // own slot's float4 base
    const int sx = lane & 7;                     // swizzle key
    const float4* sv4 = (const float4*)svw;
    float s[6] = {0.f, 0.f, 0.f, 0.f, 0.f, 0.f};
    #pragma unroll
    for (int q = 0; q < 16; ++q) {
        float4 v = sv4[sb + (q ^ sx)];
        step6(s, v.x, c1, c2, c3);
        step6(s, v.y, c1, c2, c3);
        step6(s, v.z, c1, c2, c3);
        step6(s, v.w, c1, c2, c3);
    }
    float* dl = smem + 16384;
    #pragma unroll
    for (int i = 0; i < 6; ++i) dl[t * 7 + i] = active ? s[i] : 0.f;  // clamped-garbage lanes contribute 0
    __syncthreads();                             // d visible block-wide

    // ---- truncated Horner scan over predecessors (oldest -> newest) ----
    float t6[6] = {0.f, 0.f, 0.f, 0.f, 0.f, 0.f};
    int m0 = t - MTERM; if (m0 < 0) m0 = 0;
    for (int m = m0; m < t; ++m) {
        float dm[6];
        #pragma unroll
        for (int i = 0; i < 6; ++i) dm[i] = dl[m * 7 + i];
        float nt6[6];
        #pragma unroll
        for (int i = 0; i < 6; ++i) {
            float acc = dm[i];
            #pragma unroll
            for (int jj = 0; jj < 6; ++jj) acc = fmaf(a[i * 6 + jj], t6[jj], acc);
            nt6[i] = acc;
        }
        #pragma unroll
        for (int i = 0; i < 6; ++i) t6[i] = nt6[i];
    }

    // ---- pass 2: re-run from composed start state, y -> same LDS slots ----
    float4* svw4 = (float4*)svw;
    #pragma unroll
    for (int q = 0; q < 16; ++q) {
        int idx = sb + (q ^ sx);
        float4 v = svw4[idx];
        v.x = step6(t6, v.x, c1, c2, c3);
        v.y = step6(t6, v.y, c1, c2, c3);
        v.z = step6(t6, v.z, c1, c2, c3);
        v.w = step6(t6, v.w, c1, c2, c3);
        svw4[idx] = v;
    }
    asm volatile("s_waitcnt lgkmcnt(0)" ::: "memory");  // wave's y all landed
    __builtin_amdgcn_sched_barrier(0);

    // ---- wave-contiguous store, per-wave independent (no barriers) ----
    // Instr j: 64 lanes store 1KB of consecutive addresses -> every 128B
    // line fully dirtied by one instruction (R5's store fix, kept).
    float4* op = (float4*)(out + (long long)r * T_LEN);
    const long long f4base = (long long)(cbase + w * 64) * 16;
    #pragma unroll
    for (int jj = 0; jj < 16; ++jj) {
        int o4 = jj * 64 + lane;                 // float4 idx in wave region
        int so = o4 >> 4;                        // source slot
        int tr = w * 64 + so;                    // owning thread
        int cc = cbase + tr;                     // destination chunk
        if (tr >= HISTC && cc < KCH) {
            op[f4base + o4] = svw4[o4 ^ (so & 7)];
        }
    }
}

extern "C" void kernel_launch(void* const* d_in, const int* in_sizes, int n_in,
                              void* d_out, int out_size, void* d_ws, size_t ws_size,
                              hipStream_t stream) {
    const float* x  = (const float*)d_in[0];
    const float* lg = (const float*)d_in[1];
    const float* mg = (const float*)d_in[2];
    const float* mf = (const float*)d_in[3];
    const float* mq = (const float*)d_in[4];
    const float* hg = (const float*)d_in[5];
    float* out = (float*)d_out;

    hipLaunchKernelGGL(k_fused, dim3(NBLK), dim3(NT), 0, stream,
                       x, lg, mg, mf, mq, hg, out);
}